// Round 7
// baseline (59130.170 us; speedup 1.0000x reference)
//
#include <hip/hip_runtime.h>
#include <stdint.h>

#define H 256
#define BB 64
#define TT 2048
#define G4 1024
#define LDX 264      // padded LDS row stride (elems) — proven conflict balance
#define RING 128     // xg ring slots (each [64][1024] fp32 = 256 KB)
#define NP 8         // producer blocks
#define NSCAN 4      // scan blocks (16 batches each)

typedef __attribute__((ext_vector_type(8))) short short8;
typedef __attribute__((ext_vector_type(4))) float float4_;
typedef unsigned long long ull;
typedef unsigned short ushort_t;
typedef unsigned int uint_t;

static __device__ __forceinline__ float bfhi2f(ushort_t u) {
    union { unsigned int i; float f; } v; v.i = ((unsigned int)u) << 16; return v.f;
}
static __device__ __forceinline__ ushort_t f2bf(float x) {
    union { float f; unsigned int i; } v; v.f = x;
    unsigned int u = v.i;
    return (ushort_t)((u + 0x7FFFu + ((u >> 16) & 1u)) >> 16);
}
static __device__ __forceinline__ void split2(float x, ushort_t& hi, ushort_t& lo) {
    hi = f2bf(x);
    lo = f2bf(x - bfhi2f(hi));
}
static __device__ __forceinline__ float sigm(float x) { return 1.0f / (1.0f + __expf(-x)); }
static __device__ __forceinline__ float tanh_(float x) { return 2.0f / (1.0f + __expf(-2.0f * x)) - 1.0f; }

// ---- split fp32 weights into transposed bf16 hi/lo planes: planes[mat][plane][g][k] ----
__global__ __launch_bounds__(256) void split_w(const float* __restrict__ Wx,
                                               const float* __restrict__ Wh,
                                               ushort_t* __restrict__ planes) {
    const int g = blockIdx.x & 1023;
    const int mat = blockIdx.x >> 10;
    const int k = threadIdx.x;
    const float* src = mat ? Wh : Wx;
    float v = src[(size_t)k * G4 + g];
    ushort_t hi, lo; split2(v, hi, lo);
    ushort_t* ph = planes + (size_t)mat * 2 * G4 * 256;
    ph[g * 256 + k] = hi;
    ph[(size_t)G4 * 256 + g * 256 + k] = lo;
}

// ============================================================================
// Fused LSTM, NO per-step cross-block exchange.
//   blocks 0..3   : SCAN — block sb owns batches 16sb..16sb+15 and the FULL
//                   hidden state. 16 waves; wave w owns gate-cols
//                   {g*256 + w*16 + lm : g=0..3} with Wh hi/lo fragments in
//                   256 VGPRs/lane (CU VGPR file = 2 MB >> Wh's 1 MB).
//                   Per step: acc = xg (from ring) ; 96 MFMAs/wave vs h in LDS;
//                   in-register pointwise; h hi/lo -> LDS (parity dbuf);
//                   ONE __syncthreads. Zero fabric traffic on the chain.
//   blocks 4..11  : PRODUCERS — xg[t] = x_t@Wx + bx + bh into ring slot t%128,
//                   ~100 steps ahead, throttled by scan progress. Chunk-of-32
//                   counters (release) gate the scan (acquire, 1 check / 32 steps).
//   blocks 12..255: clock ballast (round-4/6 proven, light ctrl polling).
// ============================================================================
__global__ __launch_bounds__(1024, 1) void lstm_scan(
        const float* __restrict__ x,    // [B][T][256]
        const float* __restrict__ bx,   // [1024]
        const float* __restrict__ bh,   // [1024]
        const ushort_t* __restrict__ WxTh, const ushort_t* __restrict__ WxTl,
        const ushort_t* __restrict__ WhTh, const ushort_t* __restrict__ WhTl,
        float* __restrict__ out0,       // [B][T][256]
        float* __restrict__ outh,       // [B][256]
        float* __restrict__ outc,       // [B][256]
        float* __restrict__ ring,       // [RING][64][1024] fp32
        uint_t* __restrict__ ctl) {     // [0..3]=prog, [64..127]=done32, [256]=donecnt
    union ShMem {
        struct { ushort_t xh[64 * LDX], xl[64 * LDX]; } prod;          // ~67.6 KB
        struct { ushort_t hh[2][16 * LDX], hl[2][16 * LDX]; } scan;    // ~33.8 KB
    };
    __shared__ ShMem U;
    __shared__ int bflag;

    const int tid = threadIdx.x;
    const int blk = blockIdx.x;
    uint_t* prog = ctl;
    uint_t* done32 = ctl + 64;
    uint_t* donecnt = ctl + 256;

    // ============================== BALLAST =================================
    if (blk >= NSCAN + NP) {
        if (tid >= 256) return;
        if (tid == 0) bflag = 0;
        __syncthreads();
        float a0 = 1.0f + tid * 1e-7f, a1 = 1.1f, a2 = 1.2f, a3 = 1.3f;
        float a4 = 1.4f, a5 = 1.5f, a6 = 1.6f, a7 = 1.7f;
        const float bm = 1.0000001f, cm = 1e-9f;
        for (int outer = 0; outer < 40000; ++outer) {
#pragma unroll
            for (int k = 0; k < 128; ++k) {
                a0 = __builtin_fmaf(a0, bm, cm); a1 = __builtin_fmaf(a1, bm, cm);
                a2 = __builtin_fmaf(a2, bm, cm); a3 = __builtin_fmaf(a3, bm, cm);
                a4 = __builtin_fmaf(a4, bm, cm); a5 = __builtin_fmaf(a5, bm, cm);
                a6 = __builtin_fmaf(a6, bm, cm); a7 = __builtin_fmaf(a7, bm, cm);
            }
            if ((outer & 7) == 7) {
                if (tid == 0 &&
                    __hip_atomic_load(donecnt, __ATOMIC_RELAXED, __HIP_MEMORY_SCOPE_AGENT)
                        >= (uint_t)(NSCAN + NP))
                    bflag = 1;
                __syncthreads();
                if (bflag) break;
                __syncthreads();
            }
        }
        asm volatile("" :: "v"(a0), "v"(a1), "v"(a2), "v"(a3),
                           "v"(a4), "v"(a5), "v"(a6), "v"(a7));
        return;
    }

    const int w = tid >> 6;          // wave 0..15
    const int lane = tid & 63;
    const int lq = lane >> 4, lm = lane & 15;

    // ============================== PRODUCER ================================
    if (blk >= NSCAN) {
        const int pp = blk - NSCAN;  // 0..7
        // Wx fragments: 64 gcols/wave, hi+lo = 256 VGPRs/lane
        short8 wxh[4][8], wxl[4][8];
        float bb[4];
#pragma unroll
        for (int g = 0; g < 4; ++g) {
            const int gcol = (g << 8) | (w << 4) | lm;
            const size_t wr = (size_t)gcol * 256;
#pragma unroll
            for (int kc = 0; kc < 8; ++kc) {
                wxh[g][kc] = *(const short8*)(WxTh + wr + kc * 32 + lq * 8);
                wxl[g][kc] = *(const short8*)(WxTl + wr + kc * 32 + lq * 8);
            }
            bb[g] = bx[gcol] + bh[gcol];
        }
        const int pb2 = tid >> 4, pj2 = tid & 15;   // stage role: batch row, col块

        for (int t = pp; t < TT; t += NP) {
            // throttle: never more than ~120 steps ahead of the slowest scan block
            if (tid == 0) {
                while (true) {
                    uint_t p0 = __hip_atomic_load(&prog[0], __ATOMIC_RELAXED, __HIP_MEMORY_SCOPE_AGENT);
                    uint_t p1 = __hip_atomic_load(&prog[1], __ATOMIC_RELAXED, __HIP_MEMORY_SCOPE_AGENT);
                    uint_t p2 = __hip_atomic_load(&prog[2], __ATOMIC_RELAXED, __HIP_MEMORY_SCOPE_AGENT);
                    uint_t p3 = __hip_atomic_load(&prog[3], __ATOMIC_RELAXED, __HIP_MEMORY_SCOPE_AGENT);
                    uint_t mn = p0 < p1 ? p0 : p1; mn = mn < p2 ? mn : p2; mn = mn < p3 ? mn : p3;
                    if ((uint_t)t < mn + (RING - 8)) break;
                    __builtin_amdgcn_s_sleep(8);
                }
            }
            __syncthreads();
            // stage x_t: [64][256] -> hi/lo LDS
            {
                const float* xp = x + ((size_t)pb2 * TT + t) * 256 + pj2 * 16;
                const int rb = pb2 * LDX + pj2 * 16;
#pragma unroll
                for (int q = 0; q < 4; ++q) {
                    float4_ vv = *(const float4_*)(xp + q * 4);
                    union { ushort_t u[4]; ull q8; } ph_, pl_;
#pragma unroll
                    for (int e = 0; e < 4; ++e) {
                        ushort_t hi, lo; split2(vv[e], hi, lo);
                        ph_.u[e] = hi; pl_.u[e] = lo;
                    }
                    *(ull*)(U.prod.xh + rb + q * 4) = ph_.q8;
                    *(ull*)(U.prod.xl + rb + q * 4) = pl_.q8;
                }
            }
            __syncthreads();
            // xg = x@Wx : 4 M-tiles x 4 gates x 8 kc x 3 split = 384 MFMAs/wave
            float4_ acc[4][4] = {};
#pragma unroll
            for (int m = 0; m < 4; ++m) {
#pragma unroll
                for (int kc = 0; kc < 8; ++kc) {
                    short8 ah = *(const short8*)(U.prod.xh + (m * 16 + lm) * LDX + kc * 32 + lq * 8);
                    short8 al = *(const short8*)(U.prod.xl + (m * 16 + lm) * LDX + kc * 32 + lq * 8);
#pragma unroll
                    for (int g = 0; g < 4; ++g) {
                        acc[m][g] = __builtin_amdgcn_mfma_f32_16x16x32_bf16(ah, wxh[g][kc], acc[m][g], 0, 0, 0);
                        acc[m][g] = __builtin_amdgcn_mfma_f32_16x16x32_bf16(ah, wxl[g][kc], acc[m][g], 0, 0, 0);
                        acc[m][g] = __builtin_amdgcn_mfma_f32_16x16x32_bf16(al, wxh[g][kc], acc[m][g], 0, 0, 0);
                    }
                }
            }
            // store slot: [batch][gcol], bias folded
            float* dst = ring + (size_t)(t & (RING - 1)) * 65536;
#pragma unroll
            for (int m = 0; m < 4; ++m)
#pragma unroll
                for (int g = 0; g < 4; ++g)
#pragma unroll
                    for (int r = 0; r < 4; ++r)
                        dst[(size_t)(m * 16 + lq * 4 + r) * 1024 + (g << 8) + (w << 4) + lm]
                            = acc[m][g][r] + bb[g];
            __syncthreads();   // drains all threads' stores (vmcnt) before the flag
            if (tid == 0)
                __hip_atomic_fetch_add(&done32[t >> 5], 1u, __ATOMIC_RELEASE, __HIP_MEMORY_SCOPE_AGENT);
        }
        if (tid == 0)
            __hip_atomic_fetch_add(donecnt, 1u, __ATOMIC_RELEASE, __HIP_MEMORY_SCOPE_AGENT);
        return;
    }

    // ================================ SCAN ==================================
    const int sb = blk;   // 0..3 -> batches 16sb..16sb+15
    // Wh fragments: 64 gcols/wave, hi+lo = 256 VGPRs/lane
    short8 whh[4][8], whl[4][8];
#pragma unroll
    for (int g = 0; g < 4; ++g) {
        const size_t wr = (size_t)((g << 8) | (w << 4) | lm) * 256;
#pragma unroll
        for (int kc = 0; kc < 8; ++kc) {
            whh[g][kc] = *(const short8*)(WhTh + wr + kc * 32 + lq * 8);
            whl[g][kc] = *(const short8*)(WhTl + wr + kc * 32 + lq * 8);
        }
    }
    // zero h parity-0 planes (h_{-1} = 0)
    for (int i = tid; i < 16 * LDX; i += 1024) {
        U.scan.hh[0][i] = 0; U.scan.hl[0][i] = 0;
    }
    float c_[4] = {0.0f, 0.0f, 0.0f, 0.0f};

    // wait for xg chunk 0
    if (tid == 0) {
        while (__hip_atomic_load(&done32[0], __ATOMIC_ACQUIRE, __HIP_MEMORY_SCOPE_AGENT) < 32u)
            __builtin_amdgcn_s_sleep(2);
    }
    __syncthreads();

    const int hcol = (w << 4) + lm;
    float xr[4][4], xn[4][4];
    // prefetch xg_0
    {
        const float* rp = ring + (size_t)(16 * sb) * 1024 + hcol;
#pragma unroll
        for (int g = 0; g < 4; ++g)
#pragma unroll
            for (int r = 0; r < 4; ++r)
                xr[g][r] = rp[(size_t)(lq * 4 + r) * 1024 + (g << 8)];
    }

#define SCAN_STEP(T_, P_)                                                              \
    {                                                                                  \
        const int t_ = (T_);                                                           \
        float4_ acc[4];                                                                \
        _Pragma("unroll")                                                              \
        for (int g = 0; g < 4; ++g) {                                                  \
            acc[g][0] = xr[g][0]; acc[g][1] = xr[g][1];                                \
            acc[g][2] = xr[g][2]; acc[g][3] = xr[g][3];                                \
        }                                                                              \
        if (t_ + 1 < TT) {  /* issue next-xg loads early; waited at next use */        \
            const float* rp = ring + (size_t)((t_ + 1) & (RING - 1)) * 65536           \
                              + (size_t)(16 * sb) * 1024 + hcol;                       \
            _Pragma("unroll")                                                          \
            for (int g = 0; g < 4; ++g)                                                \
                _Pragma("unroll")                                                      \
                for (int r = 0; r < 4; ++r)                                            \
                    xn[g][r] = rp[(size_t)(lq * 4 + r) * 1024 + (g << 8)];             \
        }                                                                              \
        _Pragma("unroll")                                                              \
        for (int kc = 0; kc < 8; ++kc) {                                               \
            short8 ah = *(const short8*)(U.scan.hh[P_] + lm * LDX + kc * 32 + lq * 8); \
            short8 al = *(const short8*)(U.scan.hl[P_] + lm * LDX + kc * 32 + lq * 8); \
            _Pragma("unroll")                                                          \
            for (int g = 0; g < 4; ++g) {                                              \
                acc[g] = __builtin_amdgcn_mfma_f32_16x16x32_bf16(ah, whh[g][kc], acc[g], 0, 0, 0); \
                acc[g] = __builtin_amdgcn_mfma_f32_16x16x32_bf16(ah, whl[g][kc], acc[g], 0, 0, 0); \
                acc[g] = __builtin_amdgcn_mfma_f32_16x16x32_bf16(al, whh[g][kc], acc[g], 0, 0, 0); \
            }                                                                          \
        }                                                                              \
        _Pragma("unroll")                                                              \
        for (int r = 0; r < 4; ++r) {                                                  \
            float ft = sigm(acc[0][r]), it = sigm(acc[1][r]);                          \
            float ot = sigm(acc[2][r]), ch = tanh_(acc[3][r]);                         \
            c_[r] = ft * c_[r] + it * ch;                                              \
            float hv = ot * tanh_(c_[r]);                                              \
            ushort_t hi, lo; split2(hv, hi, lo);                                       \
            U.scan.hh[(P_) ^ 1][(lq * 4 + r) * LDX + hcol] = hi;                       \
            U.scan.hl[(P_) ^ 1][(lq * 4 + r) * LDX + hcol] = lo;                       \
            out0[((size_t)(16 * sb + lq * 4 + r) * TT + t_) * H + hcol] = hv;          \
            if (t_ == TT - 1) {                                                        \
                outh[(16 * sb + lq * 4 + r) * H + hcol] = hv;                          \
                outc[(16 * sb + lq * 4 + r) * H + hcol] = c_[r];                       \
            }                                                                          \
        }                                                                              \
        if ((t_ & 31) == 16) { /* mid-chunk: gate the NEXT chunk (should be ready) */  \
            const int ck = (t_ >> 5) + 1;                                              \
            if (ck < (TT / 32) && tid == 0) {                                          \
                while (__hip_atomic_load(&done32[ck], __ATOMIC_ACQUIRE,                \
                                         __HIP_MEMORY_SCOPE_AGENT) < 32u)              \
                    __builtin_amdgcn_s_sleep(2);                                       \
            }                                                                          \
        }                                                                              \
        if ((t_ & 31) == 31 && tid == 0)                                               \
            __hip_atomic_store(&prog[sb], (uint_t)t_, __ATOMIC_RELAXED,                \
                               __HIP_MEMORY_SCOPE_AGENT);                              \
        __syncthreads();                                                               \
        _Pragma("unroll")                                                              \
        for (int g = 0; g < 4; ++g) {                                                  \
            xr[g][0] = xn[g][0]; xr[g][1] = xn[g][1];                                  \
            xr[g][2] = xn[g][2]; xr[g][3] = xn[g][3];                                  \
        }                                                                              \
    }

    for (int tt = 0; tt < TT; tt += 2) {
        SCAN_STEP(tt, 0);
        SCAN_STEP(tt + 1, 1);
    }
#undef SCAN_STEP

    if (tid == 0)
        __hip_atomic_fetch_add(donecnt, 1u, __ATOMIC_RELEASE, __HIP_MEMORY_SCOPE_AGENT);
}

extern "C" void kernel_launch(void* const* d_in, const int* in_sizes, int n_in,
                              void* d_out, int out_size, void* d_ws, size_t ws_size,
                              hipStream_t stream) {
    (void)in_sizes; (void)n_in; (void)out_size; (void)ws_size;
    const float* x  = (const float*)d_in[0];
    const float* Wx = (const float*)d_in[1];
    const float* Wh = (const float*)d_in[2];
    const float* bx = (const float*)d_in[3];
    const float* bh = (const float*)d_in[4];
    float* out0 = (float*)d_out;
    float* outh = out0 + (size_t)BB * TT * H;
    float* outc = outh + (size_t)BB * H;

    // ws: ring 32 MB | planes 2 MB | ctl 4 KB
    const size_t RING_BYTES = (size_t)RING * 64 * 1024 * 4;          // 33,554,432
    float* ring = (float*)d_ws;
    ushort_t* planes = (ushort_t*)((char*)d_ws + RING_BYTES);
    uint_t* ctl = (uint_t*)((char*)d_ws + RING_BYTES + 2097152);

    hipMemsetAsync((char*)d_ws + RING_BYTES + 2097152, 0, 4096, stream);
    split_w<<<2048, 256, 0, stream>>>(Wx, Wh, planes);
    lstm_scan<<<256, 1024, 0, stream>>>(x, bx, bh,
        planes,
        planes + (size_t)G4 * 256,
        planes + (size_t)2 * G4 * 256,
        planes + (size_t)3 * G4 * 256,
        out0, outh, outc, ring, ctl);
}